// Round 12
// baseline (172.684 us; speedup 1.0000x reference)
//
#include <hip/hip_runtime.h>

typedef unsigned short ushort;
typedef __attribute__((ext_vector_type(8))) short bf16x8;
typedef __attribute__((ext_vector_type(16))) float f32x16;
typedef __attribute__((ext_vector_type(4))) ushort us4;

#define NBATCH 32
#define ICN 256
#define OCN 256
#define HSZ 56
#define WSZ 56
#define HP 58
#define SPAT (HP*HP)            /* 3364 */
#define KTOT 2304               /* 9*256, k = (kh*3+kw)*256 + ic */
#define MTOT (NBATCH*HSZ*WSZ)   /* 100352 */
#define NT   (KTOT/64)          /* 36 K-tiles of BK=64 */

#define XP_BYTES ((size_t)NBATCH*SPAT*ICN*2)    /* 55,115,776 */
#define WD_BYTES ((size_t)OCN*KTOT*4)           /* 2,359,296  */

__device__ __forceinline__ ushort f2bf(float f) {
  union { float f; unsigned u; } c; c.f = f;
  unsigned r = c.u + 0x7FFFu + ((c.u >> 16) & 1u);
  return (ushort)(r >> 16);
}

// x [N][IC][56][56] f32 -> xp [N][58][58][IC] bf16, halo rows/cols written as 0.
__global__ void k_transpose(const float* __restrict__ x, ushort* __restrict__ xp) {
  __shared__ ushort t2[WSZ*264];   // stride 264: 8B-aligned rows, conflict-spread
  int h = blockIdx.x, n = blockIdx.y;          // h = padded row 0..57
  ushort* dst = xp + ((size_t)n*SPAT + (size_t)h*HP)*ICN;
  if (h == 0 || h == HP-1) {
    for (int e = threadIdx.x; e < HP*ICN/4; e += 256) ((us4*)dst)[e] = (us4){0,0,0,0};
    return;
  }
  const float* src = x + ((size_t)n*ICN*HSZ*WSZ) + (size_t)(h-1)*WSZ;
  for (int e = threadIdx.x; e < ICN*WSZ; e += 256) {
    int ic = e / WSZ, w = e - ic*WSZ;                 // w fastest -> coalesced read
    t2[w*264 + ic] = f2bf(src[(size_t)ic*(HSZ*WSZ) + w]);
  }
  __syncthreads();
  for (int e4 = threadIdx.x; e4 < HP*ICN/4; e4 += 256) {  // e4 = wp*64 + ic4
    int wp = e4 >> 6, ic4 = (e4 & 63) << 2;
    us4 v = (wp == 0 || wp == HP-1) ? (us4){0,0,0,0}
                                    : *(const us4*)&t2[(wp-1)*264 + ic4];
    ((us4*)dst)[e4] = v;
  }
}

// COO scatter into dense fp32 W [oc][k], duplicates sum via atomicAdd
__global__ void k_scatter(const int* __restrict__ idx, const float* __restrict__ val,
                          float* __restrict__ wd, int nnz) {
  int i = blockIdx.x*256 + threadIdx.x;
  if (i >= nnz) return;
  int id = idx[i];
  int oc = id / (ICN*9);
  int rem = id - oc*(ICN*9);
  int ic = rem / 9;
  int k9 = rem - ic*9;                                // kh*3+kw
  atomicAdd(wd + (size_t)oc*KTOT + k9*ICN + ic, val[i]);
}

// B in 32x32x16 per-lane fragment order:
// 16B unit e = ((t*4+ks)*8 + nsubg)*64 + lam holds
//   wd[oc = nsubg*32 + (lam&31)][k = (t>>2)*256 + (t&3)*64 + ks*16 + (lam>>5)*8 ..+8]
__global__ void k_convert4(const float* __restrict__ wd, ushort* __restrict__ bm4) {
  int e = blockIdx.x*256 + threadIdx.x;      // 0 .. NT*4*8*64-1
  int lam   = e & 63;
  int nsubg = (e >> 6) & 7;
  int ks    = (e >> 9) & 3;
  int t     = e >> 11;
  int oc = nsubg*32 + (lam & 31);
  int k  = (t >> 2)*256 + (t & 3)*64 + ks*16 + (lam >> 5)*8;
  const float* src = wd + (size_t)oc*KTOT + k;
  float4 v0 = *(const float4*)(src);
  float4 v1 = *(const float4*)(src + 4);
  us4 lo, hi;
  lo[0]=f2bf(v0.x); lo[1]=f2bf(v0.y); lo[2]=f2bf(v0.z); lo[3]=f2bf(v0.w);
  hi[0]=f2bf(v1.x); hi[1]=f2bf(v1.y); hi[2]=f2bf(v1.z); hi[3]=f2bf(v1.w);
  ushort* dst = bm4 + (size_t)e*8;
  *(us4*)(dst) = lo; *(us4*)(dst+4) = hi;
}

// --- 256x256 implicit-GEMM, 32x32x16 MFMA, frag-order LDS, dist-2 staging ---
// A LDS: [3 buf][u 2][ks 4][msub 4][lane 64]x16B (frag order; NO swizzle —
// reads are base+lam*16 contiguous = conflict-free; the per-lane permutation
// lives in the gld_lds SOURCE addresses).  BUFFER STRIDE = 32768 BYTES
// (R11 bug: used 16384 -> overlapping buffers).  Wave wv stages u=wv>>2,
// ks=wv&3, msub 0..3 (4 instrs).  B: global->reg from bm4 (frag order).
// Bursts b0..b3 = ks 0..3: 8 x mfma_32x32x16 each.
// ds FIFO (4-read units): enter t: [ks0,ks1]; each burst issues next unit;
// LGKM(8) uniform.  vmcnt FIFO: enter t: [stageA(t+1) 4, bvA(t) 4];
// b0 +bvB 4, VMW(4) -> bvA+stage landed; b1/b2 +stage(t+2) 2+2;
// b2 VMW(4) -> bvB landed; b3 +bvA(t+1) 4 -> 8 entering t+1.
// MIDBAR after b1 (bf1 block-wide visible); ENDBAR after b3 (bf0 drained).

#define GLD(gsrc, ldst) __builtin_amdgcn_global_load_lds( \
    (const __attribute__((address_space(1))) void*)(gsrc), \
    (__attribute__((address_space(3))) void*)(ldst), 16, 0, 0)
#define BAR()  asm volatile("s_barrier" ::: "memory")
#define VMW(N) do { asm volatile("s_waitcnt vmcnt(" #N ")" ::: "memory"); \
                    __builtin_amdgcn_sched_barrier(0); } while (0)
#define LGKM(N) do { asm volatile("s_waitcnt lgkmcnt(" #N ")" ::: "memory"); \
                     __builtin_amdgcn_sched_barrier(0); } while (0)

// stage msub = 2*HALF, 2*HALF+1 of tile T2 into buffer byte-offset B2B
#define STAGE2(T2, HALF, B2B) do { \
    const int t4_ = (T2) >> 2; const int khh_ = t4_/3, khw_ = t4_ - khh_*3; \
    const int koff_ = (khh_*HP + khw_)*256 + (((T2) & 3) << 6); \
    ushort* d_ = (ushort*)((char*)Ab + (B2B)); \
    GLD(xp + ((HALF) ? sA2 : sA0) + koff_, d_ + dOffB + (HALF)*1024); \
    GLD(xp + ((HALF) ? sA3 : sA1) + koff_, d_ + dOffB + (HALF)*1024 + 512); } while (0)

// 2 x global_load_dwordx4 (one ks: nsub 0,1) from bm4
#define GLB2(D0, D1, VOFF) \
    asm volatile("global_load_dwordx4 %0, %2, %3 offset:0\n\t" \
                 "global_load_dwordx4 %1, %2, %3 offset:1024" \
                 : "=&v"(D0), "=&v"(D1) \
                 : "v"(VOFF), "s"(bm4) : "memory")

// 4 x ds_read_b128: msub 0..3 of one ks (1KB apart, conflict-free)
#define LOADA(DST, KS, BFB) do { \
    unsigned a_ = aBase + (unsigned)((BFB) + (KS)*4096); \
    asm volatile("ds_read_b128 %0, %4 offset:0\n\t" \
                 "ds_read_b128 %1, %4 offset:1024\n\t" \
                 "ds_read_b128 %2, %4 offset:2048\n\t" \
                 "ds_read_b128 %3, %4 offset:3072" \
                 : "=&v"(DST[0]), "=&v"(DST[1]), "=&v"(DST[2]), "=&v"(DST[3]) \
                 : "v"(a_)); } while (0)

// one ks-burst: 8 x mfma_f32_32x32x16_bf16 (msub 0..3 x nsub 0..1)
#define MFMA32B(AVQ, B0, B1) do { \
    __builtin_amdgcn_s_setprio(1); \
    _Pragma("unroll") \
    for (int m_ = 0; m_ < 4; ++m_) { \
      acc[m_*2+0] = __builtin_amdgcn_mfma_f32_32x32x16_bf16(AVQ[m_], B0, acc[m_*2+0], 0, 0, 0); \
      acc[m_*2+1] = __builtin_amdgcn_mfma_f32_32x32x16_bf16(AVQ[m_], B1, acc[m_*2+1], 0, 0, 0); \
    } \
    __builtin_amdgcn_s_setprio(0); } while (0)

__global__ __launch_bounds__(512, 2) void k_gemm8(const ushort* __restrict__ xp,
                                                  const ushort* __restrict__ bm4,
                                                  const float* __restrict__ bias,
                                                  float* __restrict__ out) {
  __shared__ __align__(128) ushort Ab[3*16384];   // 96 KB: 3 x [2u][4ks][4msub][64]x16B

  const int tid = threadIdx.x;
  const int lam = tid & 63;
  const int wv  = tid >> 6;            // 0..7
  const int wr  = wv >> 2;             // 0..1  (M half = A unit u)
  const int wc  = wv & 3;              // 0..3  (N quarter)
  const int m0  = blockIdx.x * 256;

  const unsigned AbB = (unsigned)(uintptr_t)(__attribute__((address_space(3))) char*)Ab;

  // fragment read base: + bfb + ks*4096 at use; msub via offset 1024
  const unsigned aBase = AbB + wr*16384 + lam*16;
  // B voffset base: + t*32768 + ks*8192 at use; nsub via offset 1024
  const unsigned wcB = wc*2048 + lam*16;

  // staging: dest ushort offset = (u*16 + ksw*4 + msub)*512  (wave-uniform)
  const int dOffB = ((wv >> 2)*16 + (wv & 3)*4)*512;
  // per-lane source: m = m0 + u*128 + msub*32 + (lam&31);
  // k-part = ksw*16 + (lam>>5)*8  (+ koff_ per tile at issue)
  int sA0, sA1, sA2, sA3;
  {
    const int kpart = (wv & 3)*16 + (lam >> 5)*8;
    int m, n, rem, oh, ow;
    m = m0 + (wv >> 2)*128 + 0*32 + (lam & 31);
    n = m/3136; rem = m - n*3136; oh = rem/56; ow = rem - oh*56;
    sA0 = (n*SPAT + oh*HP + ow)*ICN + kpart;
    m = m0 + (wv >> 2)*128 + 1*32 + (lam & 31);
    n = m/3136; rem = m - n*3136; oh = rem/56; ow = rem - oh*56;
    sA1 = (n*SPAT + oh*HP + ow)*ICN + kpart;
    m = m0 + (wv >> 2)*128 + 2*32 + (lam & 31);
    n = m/3136; rem = m - n*3136; oh = rem/56; ow = rem - oh*56;
    sA2 = (n*SPAT + oh*HP + ow)*ICN + kpart;
    m = m0 + (wv >> 2)*128 + 3*32 + (lam & 31);
    n = m/3136; rem = m - n*3136; oh = rem/56; ow = rem - oh*56;
    sA3 = (n*SPAT + oh*HP + ow)*ICN + kpart;
  }

  f32x16 acc[8];
#pragma unroll
  for (int a = 0; a < 8; ++a) acc[a] = (f32x16)(0.f);

  // static register names (rule #20)
  bf16x8 avq0_[4], avq1_[4], avq2_[4], avq3_[4];
  bf16x8 bA0_, bA1_, bA2_, bA3_, bB0_, bB1_, bB2_, bB3_;  // bvA = ks0/1, bvB = ks2/3

  // prologue: stage A(0)->buf0, A(1)->buf1 (byte 32768!); B(0) ks0/ks1
  STAGE2(0, 0, 0); STAGE2(0, 1, 0);
  STAGE2(1, 0, 32768); STAGE2(1, 1, 32768);
  GLB2(bA0_, bA1_, wcB);                 // ks0
  GLB2(bA2_, bA3_, wcB + 8192);          // ks1
  VMW(8);                      // A(0)'s 4 stage instrs drained (per wave)
  BAR();                       // block-wide: bf0 complete
  LOADA(avq0_, 0, 0); LOADA(avq1_, 1, 0);

  int bf0b = 0, bf1b = 32768, bf2b = 65536;   // FULL 32KB buffer strides
  for (int t = 0; t < NT-2; ++t) {
    const unsigned vb = (unsigned)t*32768 + wcB;
    // b0 (ks0): +bvB(ks2,ks3); read ks2
    LOADA(avq2_, 2, bf0b);
    GLB2(bB0_, bB1_, vb + 16384);
    GLB2(bB2_, bB3_, vb + 24576);
    VMW(4);                    // bvA + stage(t+1) landed; bvB outstanding
    LGKM(8);                   // ks0 frags ready
    MFMA32B(avq0_, bA0_, bA1_);
    // b1 (ks1): read ks3; stage(t+2) msub01
    LOADA(avq3_, 3, bf0b);
    STAGE2(t+2, 0, bf2b);
    LGKM(8);                   // ks1 ready
    MFMA32B(avq1_, bA2_, bA3_);
    BAR();                     // MID: bf1 (tile t+1) block-wide visible
    // b2 (ks2): read ks0(t+1) from bf1; stage(t+2) msub23
    LOADA(avq0_, 0, bf1b);
    STAGE2(t+2, 1, bf2b);
    VMW(4);                    // bvB landed; stage(t+2) outstanding
    LGKM(8);                   // ks2 ready
    MFMA32B(avq2_, bB0_, bB1_);
    // b3 (ks3): read ks1(t+1); +bvA(t+1)
    LOADA(avq1_, 1, bf1b);
    GLB2(bA0_, bA1_, vb + 32768);
    GLB2(bA2_, bA3_, vb + 40960);
    LGKM(8);                   // ks3 ready (all bf0 reads drained)
    MFMA32B(avq3_, bB2_, bB3_);
    BAR();                     // END: bf0 safe to restage next tile
    int bt = bf0b; bf0b = bf1b; bf1b = bf2b; bf2b = bt;
  }

  // peel t = NT-2: no staging (t+2 out of range)
  {
    const unsigned vb = (unsigned)(NT-2)*32768 + wcB;
    LOADA(avq2_, 2, bf0b);
    GLB2(bB0_, bB1_, vb + 16384);
    GLB2(bB2_, bB3_, vb + 24576);
    VMW(4);                    // bvA + stage(NT-1) landed
    LGKM(8);
    MFMA32B(avq0_, bA0_, bA1_);
    LOADA(avq3_, 3, bf0b);
    LGKM(8);
    MFMA32B(avq1_, bA2_, bA3_);
    BAR();                     // MID
    LOADA(avq0_, 0, bf1b);
    VMW(0);                    // bvB landed (tail drain ok)
    LGKM(8);
    MFMA32B(avq2_, bB0_, bB1_);
    LOADA(avq1_, 1, bf1b);
    GLB2(bA0_, bA1_, vb + 32768);
    GLB2(bA2_, bA3_, vb + 40960);
    LGKM(8);
    MFMA32B(avq3_, bB2_, bB3_);
    BAR();                     // END
    int bt = bf0b; bf0b = bf1b; bf1b = bf2b; bf2b = bt;
  }

  // peel t = NT-1: no staging, no next-tile reads
  {
    const unsigned vb = (unsigned)(NT-1)*32768 + wcB;
    LOADA(avq2_, 2, bf0b);
    GLB2(bB0_, bB1_, vb + 16384);
    GLB2(bB2_, bB3_, vb + 24576);
    VMW(4);                    // bvA ready
    LGKM(8);
    MFMA32B(avq0_, bA0_, bA1_);
    LOADA(avq3_, 3, bf0b);
    LGKM(8);
    MFMA32B(avq1_, bA2_, bA3_);
    VMW(0);                    // bvB ready
    LGKM(4);
    MFMA32B(avq2_, bB0_, bB1_);
    LGKM(0);
    MFMA32B(avq3_, bB2_, bB3_);
  }

  // epilogue: D lane l: col(oc)=l&31, row m = (reg&3) + 8*(reg>>2) + 4*(l>>5)
#pragma unroll
  for (int ms = 0; ms < 4; ++ms) {
#pragma unroll
    for (int ns = 0; ns < 2; ++ns) {
      int oc = wc*64 + ns*32 + (lam & 31);
      float bvs = bias[oc];
#pragma unroll
      for (int q = 0; q < 4; ++q) {
        int m = m0 + wr*128 + ms*32 + q*8 + ((lam >> 5) << 2);
        int n = m / 3136;
        int rem = m - n*3136;   // float4 never straddles n (aligned to 4)
        float4 o;
        o.x = acc[ms*2+ns][q*4+0] + bvs;
        o.y = acc[ms*2+ns][q*4+1] + bvs;
        o.z = acc[ms*2+ns][q*4+2] + bvs;
        o.w = acc[ms*2+ns][q*4+3] + bvs;
        *(float4*)(out + ((size_t)(n*OCN + oc))*3136 + rem) = o;
      }
    }
  }
}

extern "C" void kernel_launch(void* const* d_in, const int* in_sizes, int n_in,
                              void* d_out, int out_size, void* d_ws, size_t ws_size,
                              hipStream_t stream) {
  const float* x    = (const float*)d_in[0];
  const float* wval = (const float*)d_in[1];
  const int*   widx = (const int*)d_in[2];
  const float* bias = (const float*)d_in[3];
  float* out = (float*)d_out;
  const int nnz = in_sizes[1];

  char* ws = (char*)d_ws;
  ushort* xp  = (ushort*)ws;                              // 55.1 MB
  float*  wd  = (float*)(ws + XP_BYTES);                  // 2.36 MB
  ushort* bm4 = (ushort*)(ws + XP_BYTES + WD_BYTES);      // 1.18 MB (frag-order B)

  hipMemsetAsync(wd, 0, WD_BYTES, stream);
  k_transpose<<<dim3(HP, NBATCH), 256, 0, stream>>>(x, xp);
  k_scatter<<<dim3((nnz + 255)/256), 256, 0, stream>>>(widx, wval, wd, nnz);
  k_convert4<<<dim3((NT*4*8*64)/256), 256, 0, stream>>>(wd, bm4);
  k_gemm8<<<dim3(MTOT/256), 512, 0, stream>>>(xp, bm4, bias, out);
}

// Round 13
// 149.908 us; speedup vs baseline: 1.1519x; 1.1519x over previous
//
#include <hip/hip_runtime.h>

typedef unsigned short ushort;
typedef __attribute__((ext_vector_type(8))) short bf16x8;
typedef __attribute__((ext_vector_type(4))) float f32x4;
typedef __attribute__((ext_vector_type(4))) ushort us4;

#define NBATCH 32
#define ICN 256
#define OCN 256
#define HSZ 56
#define WSZ 56
#define HP 58
#define SPAT (HP*HP)            /* 3364 */
#define KTOT 2304               /* 9*256, k = (kh*3+kw)*256 + ic */
#define MTOT (NBATCH*HSZ*WSZ)   /* 100352 = 2^11 * 7^2 */
#define NT   (KTOT/64)          /* 36 K-tiles of BK=64 */
#define BM   224                /* divides MTOT exactly: grid 448 -> 87.5% cap */

#define XP_BYTES ((size_t)NBATCH*SPAT*ICN*2)    /* 55,115,776 */
#define WD_BYTES ((size_t)OCN*KTOT*4)           /* 2,359,296  */

__device__ __forceinline__ ushort f2bf(float f) {
  union { float f; unsigned u; } c; c.f = f;
  unsigned r = c.u + 0x7FFFu + ((c.u >> 16) & 1u);
  return (ushort)(r >> 16);
}

// x [N][IC][56][56] f32 -> xp [N][58][58][IC] bf16, halo rows/cols written as 0.
__global__ void k_transpose(const float* __restrict__ x, ushort* __restrict__ xp) {
  __shared__ ushort t2[WSZ*264];
  int h = blockIdx.x, n = blockIdx.y;          // h = padded row 0..57
  ushort* dst = xp + ((size_t)n*SPAT + (size_t)h*HP)*ICN;
  if (h == 0 || h == HP-1) {
    for (int e = threadIdx.x; e < HP*ICN/4; e += 256) ((us4*)dst)[e] = (us4){0,0,0,0};
    return;
  }
  const float* src = x + ((size_t)n*ICN*HSZ*WSZ) + (size_t)(h-1)*WSZ;
  for (int e = threadIdx.x; e < ICN*WSZ; e += 256) {
    int ic = e / WSZ, w = e - ic*WSZ;
    t2[w*264 + ic] = f2bf(src[(size_t)ic*(HSZ*WSZ) + w]);
  }
  __syncthreads();
  for (int e4 = threadIdx.x; e4 < HP*ICN/4; e4 += 256) {
    int wp = e4 >> 6, ic4 = (e4 & 63) << 2;
    us4 v = (wp == 0 || wp == HP-1) ? (us4){0,0,0,0}
                                    : *(const us4*)&t2[(wp-1)*264 + ic4];
    ((us4*)dst)[e4] = v;
  }
}

// COO scatter into dense fp32 W [oc][k], duplicates sum via atomicAdd
__global__ void k_scatter(const int* __restrict__ idx, const float* __restrict__ val,
                          float* __restrict__ wd, int nnz) {
  int i = blockIdx.x*256 + threadIdx.x;
  if (i >= nnz) return;
  int id = idx[i];
  int oc = id / (ICN*9);
  int rem = id - oc*(ICN*9);
  int ic = rem / 9;
  int k9 = rem - ic*9;
  atomicAdd(wd + (size_t)oc*KTOT + k9*ICN + ic, val[i]);
}

// B in 16x16x32 per-lane fragment order (R10-proven):
// 16B unit u = ((t*2+kh)*16 + wc*4 + f)*64 + lam holds
//   wd[oc = wc*64 + f*16 + (lam&15)][k = (t>>2)*256 + (t&3)*64 + kh*32 + (lam>>4)*8 ..+8]
__global__ void k_convert3(const float* __restrict__ wd, ushort* __restrict__ bm3) {
  int e = blockIdx.x*256 + threadIdx.x;
  int lam = e & 63;
  int f   = (e >> 6) & 3;
  int wc  = (e >> 8) & 3;
  int kh  = (e >> 10) & 1;
  int t   = e >> 11;
  int oc  = wc*64 + f*16 + (lam & 15);
  int k   = (t >> 2)*256 + (t & 3)*64 + kh*32 + (lam >> 4)*8;
  const float* src = wd + (size_t)oc*KTOT + k;
  float4 v0 = *(const float4*)(src);
  float4 v1 = *(const float4*)(src + 4);
  us4 lo, hi;
  lo[0]=f2bf(v0.x); lo[1]=f2bf(v0.y); lo[2]=f2bf(v0.z); lo[3]=f2bf(v0.w);
  hi[0]=f2bf(v1.x); hi[1]=f2bf(v1.y); hi[2]=f2bf(v1.z); hi[3]=f2bf(v1.w);
  ushort* dst = bm3 + (size_t)e*8;
  *(us4*)(dst) = lo; *(us4*)(dst+4) = hi;
}

// --- 224x256 implicit-GEMM (R10 pipeline, BM=224 for 87.5% capacity) --------
// A LDS: 3 buffers x [u 2 x 112 rows x 64 k (XOR-swz oct) + 512-ushort dump].
// Buffer = 14848 ushorts (29696 B); total 87 KB -> 1 block/CU.
// Staging: 28 real gld_lds/tile by waves 0-6 (4 each, j=wv*4+i covering rows
// 8j..8j+7); wave 7 issues 4 DUMMY loads into the target buffer's dump slot
// so every wave's vmcnt FIFO is identical.  vmcnt schedule == R10:
// enter t: [stage(t+1) 4, bvA 4]; b0 +bvB, VMW(4); b1/b2 +stage(t+2) 2+2;
// b2 VMW(4); b3 +bvA(t+1).  Never vmcnt(0) in main loop.
// ds FIFO: bursts read 4/3/4/3 (mh0=4 frags, mh1=3); uniform LGKM(7).
// Bursts: (kh0,mh0)=16 MFMA, (kh0,mh1)=12, (kh1,mh0)=16, (kh1,mh1)=12.

#define GLD(gsrc, ldst) __builtin_amdgcn_global_load_lds( \
    (const __attribute__((address_space(1))) void*)(gsrc), \
    (__attribute__((address_space(3))) void*)(ldst), 16, 0, 0)
#define BAR()  asm volatile("s_barrier" ::: "memory")
#define VMW(N) do { asm volatile("s_waitcnt vmcnt(" #N ")" ::: "memory"); \
                    __builtin_amdgcn_sched_barrier(0); } while (0)
#define LGKM(N) do { asm volatile("s_waitcnt lgkmcnt(" #N ")" ::: "memory"); \
                     __builtin_amdgcn_sched_barrier(0); } while (0)

#define BUF_US  14848          /* ushorts per buffer (incl. dump) */
#define BUF_B   29696          /* bytes per buffer */

// stage slot pair (PAIR=0: slots 0,1; PAIR=1: slots 2,3) of tile T2 into
// buffer with ushort base BUFUS
#define STAGE2X(T2, PAIR, BUFUS) do { \
    const int t4_ = (T2) >> 2; const int khh_ = t4_/3, khw_ = t4_ - khh_*3; \
    const int koff_ = (khh_*HP + khw_)*256 + (((T2) & 3) << 6); \
    ushort* b_ = Ab + (BUFUS); \
    GLD(xp + ((PAIR) ? sA2 : sA0) + koff_, b_ + ((PAIR) ? dO2 : dO0)); \
    GLD(xp + ((PAIR) ? sA3 : sA1) + koff_, b_ + ((PAIR) ? dO3 : dO1)); } while (0)

// B fragment loads: 4 x global_load_dwordx4 (contiguous 1KB runs, L2 hit)
#define GLB(DST, VOFF) \
    asm volatile("global_load_dwordx4 %0, %4, %5 offset:0\n\t" \
                 "global_load_dwordx4 %1, %4, %5 offset:1024\n\t" \
                 "global_load_dwordx4 %2, %4, %5 offset:2048\n\t" \
                 "global_load_dwordx4 %3, %4, %5 offset:3072" \
                 : "=&v"(DST[0]), "=&v"(DST[1]), "=&v"(DST[2]), "=&v"(DST[3]) \
                 : "v"(VOFF), "s"(bm3) : "memory")

// mh0: 4 frags (rows 0..63 of this wave's u)
#define LOADA4(DST, KH, BFB) do { \
    unsigned a_ = ((KH) ? aL1v : aL0v) + (unsigned)(BFB); \
    asm volatile("ds_read_b128 %0, %4 offset:0\n\t" \
                 "ds_read_b128 %1, %4 offset:2048\n\t" \
                 "ds_read_b128 %2, %4 offset:4096\n\t" \
                 "ds_read_b128 %3, %4 offset:6144" \
                 : "=&v"(DST[0]), "=&v"(DST[1]), "=&v"(DST[2]), "=&v"(DST[3]) \
                 : "v"(a_)); } while (0)

// mh1: 3 frags (rows 64..111)
#define LOADA3(DST, KH, BFB) do { \
    unsigned a_ = ((KH) ? aL1v : aL0v) + (unsigned)((BFB) + 8192); \
    asm volatile("ds_read_b128 %0, %3 offset:0\n\t" \
                 "ds_read_b128 %1, %3 offset:2048\n\t" \
                 "ds_read_b128 %2, %3 offset:4096" \
                 : "=&v"(DST[0]), "=&v"(DST[1]), "=&v"(DST[2]) \
                 : "v"(a_)); } while (0)

#define MFMA16(AV, BV) do { \
    __builtin_amdgcn_s_setprio(1); \
    _Pragma("unroll") \
    for (int f_ = 0; f_ < 4; ++f_) { \
      _Pragma("unroll") \
      for (int n_ = 0; n_ < 4; ++n_) \
        acc[f_][n_] = __builtin_amdgcn_mfma_f32_16x16x32_bf16( \
            AV[f_], BV[n_], acc[f_][n_], 0, 0, 0); \
    } \
    __builtin_amdgcn_s_setprio(0); } while (0)

#define MFMA12(AV, BV) do { \
    __builtin_amdgcn_s_setprio(1); \
    _Pragma("unroll") \
    for (int f_ = 0; f_ < 3; ++f_) { \
      _Pragma("unroll") \
      for (int n_ = 0; n_ < 4; ++n_) \
        acc[4+f_][n_] = __builtin_amdgcn_mfma_f32_16x16x32_bf16( \
            AV[f_], BV[n_], acc[4+f_][n_], 0, 0, 0); \
    } \
    __builtin_amdgcn_s_setprio(0); } while (0)

__global__ __launch_bounds__(512, 2) void k_gemm8(const ushort* __restrict__ xp,
                                                  const ushort* __restrict__ bm3,
                                                  const float* __restrict__ bias,
                                                  float* __restrict__ out) {
  __shared__ __align__(128) ushort Ab[3*BUF_US];   // 87 KB

  const int tid = threadIdx.x;
  const int lam = tid & 63;
  const int wv  = tid >> 6;            // 0..7
  const int wr  = wv >> 2;             // 0..1  (M half = A unit u, 112 rows)
  const int wc  = wv & 3;              // 0..3  (N quarter)
  const int la  = lam & 15;
  const int m0  = blockIdx.x * BM;

  const unsigned AbB = (unsigned)(uintptr_t)(__attribute__((address_space(3))) char*)Ab;

  // A read bases: byte = buf + u(wr)*14336 + mh*8192(at use) + r*128 + p*16,
  // r = f*16+la, p = (kh*4 + oq) ^ (la&7), oq = lam>>4.
  const int q0 = (lam >> 4) ^ (la & 7);
  const unsigned aL0v = AbB + wr*14336 + la*128 + q0*16;
  const unsigned aL1v = AbB + wr*14336 + la*128 + (q0 ^ 4)*16;

  // B voffset base (bm3, 16x16 frag order): + t*32768 + kh*16384 at use
  const unsigned wcB = wc*4096 + lam*16;

  // staging: waves 0-6 real (instr j = wv*4+i, rows 8j..8j+7, j=0..27);
  // wave 7: 4 dummies into this buffer's dump slot (ushort 14336).
  // logical oct o = (lam&7) ^ (lam>>3)  (phys = lam&7, r&7 = lam>>3).
  int sA0, sA1, sA2, sA3;
  int dO0, dO1, dO2, dO3;
  if (wv < 7) {
    const int oA = (lam & 7) ^ (lam >> 3);
    int m, n, rem, oh, ow, r;
    r = (wv*4 + 0)*8 + (lam >> 3);
    m = m0 + r; n = m/3136; rem = m - n*3136; oh = rem/56; ow = rem - oh*56;
    sA0 = (n*SPAT + oh*HP + ow)*ICN + oA*8;  dO0 = (wv*4 + 0)*512;
    r = (wv*4 + 1)*8 + (lam >> 3);
    m = m0 + r; n = m/3136; rem = m - n*3136; oh = rem/56; ow = rem - oh*56;
    sA1 = (n*SPAT + oh*HP + ow)*ICN + oA*8;  dO1 = (wv*4 + 1)*512;
    r = (wv*4 + 2)*8 + (lam >> 3);
    m = m0 + r; n = m/3136; rem = m - n*3136; oh = rem/56; ow = rem - oh*56;
    sA2 = (n*SPAT + oh*HP + ow)*ICN + oA*8;  dO2 = (wv*4 + 2)*512;
    r = (wv*4 + 3)*8 + (lam >> 3);
    m = m0 + r; n = m/3136; rem = m - n*3136; oh = rem/56; ow = rem - oh*56;
    sA3 = (n*SPAT + oh*HP + ow)*ICN + oA*8;  dO3 = (wv*4 + 3)*512;
  } else {
    sA0 = sA1 = sA2 = sA3 = 0;               // xp + koff: always valid
    dO0 = dO1 = dO2 = dO3 = 14336;           // dump slot (per buffer)
  }

  f32x4 acc[7][4];
#pragma unroll
  for (int a = 0; a < 7; ++a)
#pragma unroll
    for (int b = 0; b < 4; ++b) acc[a][b] = (f32x4){0.f, 0.f, 0.f, 0.f};

  // static register names (rule #20)
  bf16x8 avq0_[4], avq1_[3], avq2_[4], avq3_[3], bvA_[4], bvB_[4];

  // prologue: stage A(0)->buf0, A(1)->buf1; B(0,kh0).
  // VMW(4): drains 8 oldest (= both stage sets); bvA may remain in flight.
  STAGE2X(0, 0, 0);       STAGE2X(0, 1, 0);
  STAGE2X(1, 0, BUF_US);  STAGE2X(1, 1, BUF_US);
  GLB(bvA_, wcB);
  VMW(4);
  BAR();
  LOADA4(avq0_, 0, 0); LOADA3(avq1_, 0, 0);

  int bf0b = 0, bf1b = BUF_B, bf2b = 2*BUF_B;          // READ byte offsets
  int bf2u = 2*BUF_US;                                  // STAGE ushort offset
  for (int t = 0; t < NT-2; ++t) {
    const unsigned vb = (unsigned)t*32768 + wcB;
    // b0 (kh0,mh0): +bvB; read (kh1,mh0)
    LOADA4(avq2_, 1, bf0b);
    GLB(bvB_, vb + 16384);
    VMW(4);                    // bvA + stage(t+1) landed
    LGKM(7);                   // avq0 ready
    MFMA16(avq0_, bvA_);
    // b1 (kh0,mh1): read (kh1,mh1); stage(t+2) slots 0,1
    LOADA3(avq3_, 1, bf0b);
    STAGE2X(t+2, 0, bf2u);
    LGKM(7);                   // avq1 ready
    MFMA12(avq1_, bvA_);
    BAR();                     // MID: bf1 (tile t+1) block-wide visible
    // b2 (kh1,mh0): read (kh0,mh0) of t+1 from bf1; stage(t+2) slots 2,3
    LOADA4(avq0_, 0, bf1b);
    STAGE2X(t+2, 1, bf2u);
    VMW(4);                    // bvB landed; stage(t+2) outstanding
    LGKM(7);                   // avq2 ready
    MFMA16(avq2_, bvB_);
    // b3 (kh1,mh1): read (kh0,mh1) of t+1; +bvA(t+1)
    LOADA3(avq1_, 0, bf1b);
    GLB(bvA_, vb + 32768);
    LGKM(7);                   // avq3 ready (all bf0 reads drained)
    MFMA12(avq3_, bvB_);
    BAR();                     // END: bf0 safe to restage next tile
    int bt = bf0b; bf0b = bf1b; bf1b = bf2b; bf2b = bt;
    bf2u = bf2b / 2;
  }

  // peel t = NT-2: no staging (t+2 out of range)
  {
    const unsigned vb = (unsigned)(NT-2)*32768 + wcB;
    LOADA4(avq2_, 1, bf0b);
    GLB(bvB_, vb + 16384);
    VMW(4);                    // bvA + stage(NT-1) landed
    LGKM(7);
    MFMA16(avq0_, bvA_);
    LOADA3(avq3_, 1, bf0b);
    LGKM(7);
    MFMA12(avq1_, bvA_);
    BAR();                     // MID
    LOADA4(avq0_, 0, bf1b);
    VMW(0);                    // bvB landed (tail drain ok)
    LGKM(7);
    MFMA16(avq2_, bvB_);
    LOADA3(avq1_, 0, bf1b);
    GLB(bvA_, vb + 32768);
    LGKM(7);
    MFMA12(avq3_, bvB_);
    BAR();                     // END
    int bt = bf0b; bf0b = bf1b; bf1b = bf2b; bf2b = bt;
  }

  // peel t = NT-1: no staging, no next-tile reads
  {
    const unsigned vb = (unsigned)(NT-1)*32768 + wcB;
    LOADA4(avq2_, 1, bf0b);
    GLB(bvB_, vb + 16384);
    VMW(4);                    // bvA ready
    LGKM(7);
    MFMA16(avq0_, bvA_);
    LOADA3(avq3_, 1, bf0b);
    LGKM(7);
    MFMA12(avq1_, bvA_);
    VMW(0);                    // bvB ready
    LGKM(3);                   // avq2 ready (avq3 still in flight)
    MFMA16(avq2_, bvB_);
    LGKM(0);                   // avq3 ready
    MFMA12(avq3_, bvB_);
  }

  // epilogue: lane l -> col(oc) = la, rows m = base + (l>>4)*4 + j
#pragma unroll
  for (int nn = 0; nn < 4; ++nn) {
    int oc = wc*64 + nn*16 + la;
    float bvs = bias[oc];
#pragma unroll
    for (int mf = 0; mf < 7; ++mf) {
      int m = m0 + wr*112 + mf*16 + ((lam >> 4) << 2);
      int n = m / 3136;
      int rem = m - n*3136;     // float4 never straddles n (m aligned to 4)
      float4 o;
      o.x = acc[mf][nn][0] + bvs;
      o.y = acc[mf][nn][1] + bvs;
      o.z = acc[mf][nn][2] + bvs;
      o.w = acc[mf][nn][3] + bvs;
      *(float4*)(out + ((size_t)(n*OCN + oc))*3136 + rem) = o;
    }
  }
}

extern "C" void kernel_launch(void* const* d_in, const int* in_sizes, int n_in,
                              void* d_out, int out_size, void* d_ws, size_t ws_size,
                              hipStream_t stream) {
  const float* x    = (const float*)d_in[0];
  const float* wval = (const float*)d_in[1];
  const int*   widx = (const int*)d_in[2];
  const float* bias = (const float*)d_in[3];
  float* out = (float*)d_out;
  const int nnz = in_sizes[1];

  char* ws = (char*)d_ws;
  ushort* xp  = (ushort*)ws;                              // 55.1 MB
  float*  wd  = (float*)(ws + XP_BYTES);                  // 2.36 MB
  ushort* bm3 = (ushort*)(ws + XP_BYTES + WD_BYTES);      // 1.125 MB (frag-order B)

  hipMemsetAsync(wd, 0, WD_BYTES, stream);
  k_transpose<<<dim3(HP, NBATCH), 256, 0, stream>>>(x, xp);
  k_scatter<<<dim3((nnz + 255)/256), 256, 0, stream>>>(widx, wval, wd, nnz);
  k_convert3<<<dim3((NT*2*16*64)/256), 256, 0, stream>>>(wd, bm3);
  k_gemm8<<<dim3(MTOT/BM), 512, 0, stream>>>(xp, bm3, bias, out);
}

// Round 14
// 148.890 us; speedup vs baseline: 1.1598x; 1.0068x over previous
//
#include <hip/hip_runtime.h>

typedef unsigned short ushort;
typedef __attribute__((ext_vector_type(8))) short bf16x8;
typedef __attribute__((ext_vector_type(4))) float f32x4;
typedef __attribute__((ext_vector_type(4))) ushort us4;

#define NBATCH 32
#define ICN 256
#define OCN 256
#define HSZ 56
#define WSZ 56
#define HP 58
#define SPAT (HP*HP)            /* 3364 */
#define KTOT 2304               /* 9*256, k = (kh*3+kw)*256 + ic */
#define MTOT (NBATCH*HSZ*WSZ)   /* 100352 = 2^11 * 7^2 */
#define NT2  (KTOT/128)         /* 18 K-tiles of BK=128 */
#define BM   224                /* grid 448 -> 87.5% capacity */

#define XP_BYTES ((size_t)NBATCH*SPAT*ICN*2)    /* 55,115,776 */
#define WD_BYTES ((size_t)OCN*KTOT*4)           /* 2,359,296  */

__device__ __forceinline__ ushort f2bf(float f) {
  union { float f; unsigned u; } c; c.f = f;
  unsigned r = c.u + 0x7FFFu + ((c.u >> 16) & 1u);
  return (ushort)(r >> 16);
}

// x [N][IC][56][56] f32 -> xp [N][58][58][IC] bf16, halo rows/cols written as 0.
__global__ void k_transpose(const float* __restrict__ x, ushort* __restrict__ xp) {
  __shared__ ushort t2[WSZ*264];
  int h = blockIdx.x, n = blockIdx.y;
  ushort* dst = xp + ((size_t)n*SPAT + (size_t)h*HP)*ICN;
  if (h == 0 || h == HP-1) {
    for (int e = threadIdx.x; e < HP*ICN/4; e += 256) ((us4*)dst)[e] = (us4){0,0,0,0};
    return;
  }
  const float* src = x + ((size_t)n*ICN*HSZ*WSZ) + (size_t)(h-1)*WSZ;
  for (int e = threadIdx.x; e < ICN*WSZ; e += 256) {
    int ic = e / WSZ, w = e - ic*WSZ;
    t2[w*264 + ic] = f2bf(src[(size_t)ic*(HSZ*WSZ) + w]);
  }
  __syncthreads();
  for (int e4 = threadIdx.x; e4 < HP*ICN/4; e4 += 256) {
    int wp = e4 >> 6, ic4 = (e4 & 63) << 2;
    us4 v = (wp == 0 || wp == HP-1) ? (us4){0,0,0,0}
                                    : *(const us4*)&t2[(wp-1)*264 + ic4];
    ((us4*)dst)[e4] = v;
  }
}

__global__ void k_scatter(const int* __restrict__ idx, const float* __restrict__ val,
                          float* __restrict__ wd, int nnz) {
  int i = blockIdx.x*256 + threadIdx.x;
  if (i >= nnz) return;
  int id = idx[i];
  int oc = id / (ICN*9);
  int rem = id - oc*(ICN*9);
  int ic = rem / 9;
  int k9 = rem - ic*9;
  atomicAdd(wd + (size_t)oc*KTOT + k9*ICN + ic, val[i]);
}

// B in 16x16x32 per-lane fragment order (R10-proven, t64-granular):
// 16B unit u = ((t64*2+kh)*16 + wc*4 + f)*64 + lam holds
//   wd[oc = wc*64+f*16+(lam&15)][k = (t64>>2)*256+(t64&3)*64+kh*32+(lam>>4)*8 ..+8]
__global__ void k_convert3(const float* __restrict__ wd, ushort* __restrict__ bm3) {
  int e = blockIdx.x*256 + threadIdx.x;
  int lam = e & 63;
  int f   = (e >> 6) & 3;
  int wc  = (e >> 8) & 3;
  int kh  = (e >> 10) & 1;
  int t   = e >> 11;
  int oc  = wc*64 + f*16 + (lam & 15);
  int k   = (t >> 2)*256 + (t & 3)*64 + kh*32 + (lam >> 4)*8;
  const float* src = wd + (size_t)oc*KTOT + k;
  float4 v0 = *(const float4*)(src);
  float4 v1 = *(const float4*)(src + 4);
  us4 lo, hi;
  lo[0]=f2bf(v0.x); lo[1]=f2bf(v0.y); lo[2]=f2bf(v0.z); lo[3]=f2bf(v0.w);
  hi[0]=f2bf(v1.x); hi[1]=f2bf(v1.y); hi[2]=f2bf(v1.z); hi[3]=f2bf(v1.w);
  ushort* dst = bm3 + (size_t)e*8;
  *(us4*)(dst) = lo; *(us4*)(dst+4) = hi;
}

// --- 224x256 implicit-GEMM, BK=128, ONE barrier per K-128 -------------------
// A LDS: 2 buffers x [khHalf 2][u 2][112 r][64 k] (each half = R13's verified
// unit: XOR-swz oct p = o ^ (r&7), reads 2 lanes/bank).  Buffer = 29184 us
// (58368 B) incl pad; total 114 KB -> 1 block/CU.  Staging: 56 gld_lds/tile =
// 8 waves x 7 (waves 0-3 -> half A = t64 even, 4-7 -> half B = t64 odd; instr
// i covers rows 8j'..8j'+7, j' = (wv&3)*7+i; u-boundary at 112 = 14x8: clean).
// B: global->reg, 2 sets, in-tile refills b2/b4/b6/b7post (2-burst lead).
// Bursts b0..b7 = (kq0..kq3) x (mh0 16-MFMA, mh1 12-MFMA).
// vmcnt induction (per wave; order per burst: reads,STAGE,GLB,VMW,LGKM,MFMA):
//  enter t: [A4=kq0, B4=kq1] = 8
//  b0:+s0=9  VMW(5) drains kq0   | b1:+s1=6
//  b2:+s2+A4(kq2)=11 VMW(7) drains kq1 | b3:+s3=8
//  b4:+s4+B4(kq3)=13 VMW(6) drains kq2 | b5:+s5=7
//  b6:+s6+A4(kq0')=12 VMW(6) drains kq3
//  b7: LGKM(0) MFMA; +B4(kq1')=10; VMW(8) drains s5,s6 -> [A4,B4]=8; BAR. qed
// ds induction: b0 issues 4+3, LGKM(3); then alternate issue-4/LGKM(4),
// issue-3/LGKM(3); b7 LGKM(0).  Never vmcnt(0) in the main loop.

#define GLD(gsrc, ldst) __builtin_amdgcn_global_load_lds( \
    (const __attribute__((address_space(1))) void*)(gsrc), \
    (__attribute__((address_space(3))) void*)(ldst), 16, 0, 0)
#define BAR()  asm volatile("s_barrier" ::: "memory")
#define VMW(N) do { asm volatile("s_waitcnt vmcnt(" #N ")" ::: "memory"); \
                    __builtin_amdgcn_sched_barrier(0); } while (0)
#define LGKM(N) do { asm volatile("s_waitcnt lgkmcnt(" #N ")" ::: "memory"); \
                     __builtin_amdgcn_sched_barrier(0); } while (0)

#define BUF2_US 29184          /* ushorts per buffer (2 halves + 512 pad) */
#define BUF2_B  58368

// one stage instr: source srcA_I + koffw, dest = stage-buf + dO_I
#define STAGE1(SRC, DO, SU) \
    GLD(xp + (SRC) + koffw, Ab + (SU) + (DO))

#define GLB(DST, VOFF) \
    asm volatile("global_load_dwordx4 %0, %4, %5 offset:0\n\t" \
                 "global_load_dwordx4 %1, %4, %5 offset:1024\n\t" \
                 "global_load_dwordx4 %2, %4, %5 offset:2048\n\t" \
                 "global_load_dwordx4 %3, %4, %5 offset:3072" \
                 : "=&v"(DST[0]), "=&v"(DST[1]), "=&v"(DST[2]), "=&v"(DST[3]) \
                 : "v"(VOFF), "s"(bm3) : "memory")

// mh0: 4 frags (rows 0..63 of this wave's u); BASE = aL0v/aL1v (+28672 for half B)
#define LOADA4(DST, BASE, OFF) do { \
    unsigned a_ = (BASE) + (unsigned)(OFF); \
    asm volatile("ds_read_b128 %0, %4 offset:0\n\t" \
                 "ds_read_b128 %1, %4 offset:2048\n\t" \
                 "ds_read_b128 %2, %4 offset:4096\n\t" \
                 "ds_read_b128 %3, %4 offset:6144" \
                 : "=&v"(DST[0]), "=&v"(DST[1]), "=&v"(DST[2]), "=&v"(DST[3]) \
                 : "v"(a_)); } while (0)

// mh1: 3 frags (rows 64..111)
#define LOADA3(DST, BASE, OFF) do { \
    unsigned a_ = (BASE) + (unsigned)((OFF) + 8192); \
    asm volatile("ds_read_b128 %0, %3 offset:0\n\t" \
                 "ds_read_b128 %1, %3 offset:2048\n\t" \
                 "ds_read_b128 %2, %3 offset:4096" \
                 : "=&v"(DST[0]), "=&v"(DST[1]), "=&v"(DST[2]) \
                 : "v"(a_)); } while (0)

#define MFMA16(AV, BV) do { \
    __builtin_amdgcn_s_setprio(1); \
    _Pragma("unroll") \
    for (int f_ = 0; f_ < 4; ++f_) { \
      _Pragma("unroll") \
      for (int n_ = 0; n_ < 4; ++n_) \
        acc[f_][n_] = __builtin_amdgcn_mfma_f32_16x16x32_bf16( \
            AV[f_], BV[n_], acc[f_][n_], 0, 0, 0); \
    } \
    __builtin_amdgcn_s_setprio(0); } while (0)

#define MFMA12(AV, BV) do { \
    __builtin_amdgcn_s_setprio(1); \
    _Pragma("unroll") \
    for (int f_ = 0; f_ < 3; ++f_) { \
      _Pragma("unroll") \
      for (int n_ = 0; n_ < 4; ++n_) \
        acc[4+f_][n_] = __builtin_amdgcn_mfma_f32_16x16x32_bf16( \
            AV[f_], BV[n_], acc[4+f_][n_], 0, 0, 0); \
    } \
    __builtin_amdgcn_s_setprio(0); } while (0)

__global__ __launch_bounds__(512, 2) void k_gemm8(const ushort* __restrict__ xp,
                                                  const ushort* __restrict__ bm3,
                                                  const float* __restrict__ bias,
                                                  float* __restrict__ out) {
  __shared__ __align__(128) ushort Ab[2*BUF2_US];   // 114 KB

  const int tid = threadIdx.x;
  const int lam = tid & 63;
  const int wv  = tid >> 6;            // 0..7
  const int wr  = wv >> 2;             // 0..1  (M half = u, 112 rows)
  const int wc  = wv & 3;              // 0..3  (N quarter)
  const int la  = lam & 15;
  const int hv  = wv >> 2;             // staging half (A=even t64, B=odd)
  const int m0  = blockIdx.x * BM;

  const unsigned AbB = (unsigned)(uintptr_t)(__attribute__((address_space(3))) char*)Ab;

  // read bases (byte): buf + half*28672 + u(wr)*14336 + mh*8192 + r*128 + p*16
  // r = f*16+la, p = oq ^ (la&7) (+4 for kq-odd), oq = lam>>4.
  const int q0 = (lam >> 4) ^ (la & 7);
  const unsigned aL0v = AbB + wr*14336 + la*128 + q0*16;         // kq even
  const unsigned aL1v = AbB + wr*14336 + la*128 + (q0 ^ 4)*16;   // kq odd

  // B voffset base (bm3): + t64*32768 + kh*16384 at use
  const unsigned wcB = wc*4096 + lam*16;

  // staging: 7 instrs/wave; j' = (wv&3)*7 + i, rows 8j'..8j'+7 of this half;
  // dest ushort = hv*14336 + j'*512; per-lane row = 8j' + (lam>>3),
  // m = m0 + row; logical oct o = (lam&7)^(lam>>3); k = koff(t64) + o*8.
  int srcA0, srcA1, srcA2, srcA3, srcA4, srcA5, srcA6;
  int dO0, dO1, dO2, dO3, dO4, dO5, dO6;
  {
    const int oA8 = ((lam & 7) ^ (lam >> 3)) * 8;
    const int jb = (wv & 3)*7;
    int m, n, rem, oh, ow;
#define MKSRC(I, SV, DV) do { \
    int row_ = (jb + (I))*8 + (lam >> 3); \
    m = m0 + row_; n = m/3136; rem = m - n*3136; oh = rem/56; ow = rem - oh*56; \
    SV = (n*SPAT + oh*HP + ow)*ICN + oA8; \
    DV = hv*14336 + (jb + (I))*512; } while (0)
    MKSRC(0, srcA0, dO0); MKSRC(1, srcA1, dO1); MKSRC(2, srcA2, dO2);
    MKSRC(3, srcA3, dO3); MKSRC(4, srcA4, dO4); MKSRC(5, srcA5, dO5);
    MKSRC(6, srcA6, dO6);
#undef MKSRC
  }

  f32x4 acc[7][4];
#pragma unroll
  for (int a = 0; a < 7; ++a)
#pragma unroll
    for (int b = 0; b < 4; ++b) acc[a][b] = (f32x4){0.f, 0.f, 0.f, 0.f};

  // static register names (rule #20)
  bf16x8 avq0_[4], avq1_[3], avq2_[4], avq3_[3], bvA_[4], bvB_[4];

  // prologue: stage tile 0 (t64 = hv) into buf0; B(0) kq0,kq1.
  {
    const int t64 = hv;
    const int t4_ = t64 >> 2; const int khh_ = t4_/3, khw_ = t4_ - khh_*3;
    const int koffw = (khh_*HP + khw_)*256 + ((t64 & 3) << 6);
    STAGE1(srcA0, dO0, 0); STAGE1(srcA1, dO1, 0); STAGE1(srcA2, dO2, 0);
    STAGE1(srcA3, dO3, 0); STAGE1(srcA4, dO4, 0); STAGE1(srcA5, dO5, 0);
    STAGE1(srcA6, dO6, 0);
  }
  GLB(bvA_, wcB);                 // kq0(0)
  GLB(bvB_, wcB + 16384);         // kq1(0)
  VMW(8);                         // 7 stages drained; [A4,B4] outstanding
  BAR();

  for (int t = 0; t < NT2-1; ++t) {
    const unsigned rb = (unsigned)((t & 1) ? BUF2_B : 0);       // read buf bytes
    const int su = ((t & 1) ^ 1) * BUF2_US;                     // stage buf us
    const unsigned vb = (unsigned)t*65536 + wcB;
    // staging koff for tile t+1 (this wave's half: t64 = 2(t+1) + hv)
    int koffw;
    {
      const int t64 = 2*(t+1) + hv;
      const int t4_ = t64 >> 2; const int khh_ = t4_/3, khw_ = t4_ - khh_*3;
      koffw = (khh_*HP + khw_)*256 + ((t64 & 3) << 6);
    }
    // b0 (kq0,mh0)
    LOADA4(avq0_, aL0v, rb); LOADA3(avq1_, aL0v, rb);
    STAGE1(srcA0, dO0, su);
    VMW(5);  LGKM(3);  MFMA16(avq0_, bvA_);
    // b1 (kq0,mh1)
    LOADA4(avq2_, aL1v, rb);
    STAGE1(srcA1, dO1, su);
    LGKM(4);  MFMA12(avq1_, bvA_);
    // b2 (kq1,mh0)
    LOADA3(avq3_, aL1v, rb);
    STAGE1(srcA2, dO2, su);
    GLB(bvA_, vb + 32768);          // kq2(t)
    VMW(7);  LGKM(3);  MFMA16(avq2_, bvB_);
    // b3 (kq1,mh1)
    LOADA4(avq0_, aL0v, rb + 28672);
    STAGE1(srcA3, dO3, su);
    LGKM(4);  MFMA12(avq3_, bvB_);
    // b4 (kq2,mh0)
    LOADA3(avq1_, aL0v, rb + 28672);
    STAGE1(srcA4, dO4, su);
    GLB(bvB_, vb + 49152);          // kq3(t)
    VMW(6);  LGKM(3);  MFMA16(avq0_, bvA_);
    // b5 (kq2,mh1)
    LOADA4(avq2_, aL1v, rb + 28672);
    STAGE1(srcA5, dO5, su);
    LGKM(4);  MFMA12(avq1_, bvA_);
    // b6 (kq3,mh0)
    LOADA3(avq3_, aL1v, rb + 28672);
    STAGE1(srcA6, dO6, su);
    GLB(bvA_, vb + 65536);          // kq0(t+1)
    VMW(6);  LGKM(3);  MFMA16(avq2_, bvB_);
    // b7 (kq3,mh1)
    LGKM(0);  MFMA12(avq3_, bvB_);
    GLB(bvB_, vb + 81920);          // kq1(t+1)  (after bvB's last use)
    VMW(8);                         // s0..s6(t+1) landed; [kq0',kq1'] in flight
    BAR();
  }

  // peel t = NT2-1: no staging; in-tile kq2/kq3 refills only
  {
    const int t = NT2-1;
    const unsigned rb = (unsigned)((t & 1) ? BUF2_B : 0);
    const unsigned vb = (unsigned)t*65536 + wcB;
    LOADA4(avq0_, aL0v, rb); LOADA3(avq1_, aL0v, rb);
    VMW(4);  LGKM(3);  MFMA16(avq0_, bvA_);
    LOADA4(avq2_, aL1v, rb);
    LGKM(4);  MFMA12(avq1_, bvA_);
    LOADA3(avq3_, aL1v, rb);
    GLB(bvA_, vb + 32768);          // kq2
    VMW(4);  LGKM(3);  MFMA16(avq2_, bvB_);
    LOADA4(avq0_, aL0v, rb + 28672);
    LGKM(4);  MFMA12(avq3_, bvB_);
    LOADA3(avq1_, aL0v, rb + 28672);
    GLB(bvB_, vb + 49152);          // kq3
    VMW(4);  LGKM(3);  MFMA16(avq0_, bvA_);
    LOADA4(avq2_, aL1v, rb + 28672);
    LGKM(4);  MFMA12(avq1_, bvA_);
    LOADA3(avq3_, aL1v, rb + 28672);
    VMW(0);  LGKM(3);  MFMA16(avq2_, bvB_);
    LGKM(0);  MFMA12(avq3_, bvB_);
  }

  // epilogue: lane l -> col(oc) = la, rows m = base + (l>>4)*4 + j
#pragma unroll
  for (int nn = 0; nn < 4; ++nn) {
    int oc = wc*64 + nn*16 + la;
    float bvs = bias[oc];
#pragma unroll
    for (int mf = 0; mf < 7; ++mf) {
      int m = m0 + wr*112 + mf*16 + ((lam >> 4) << 2);
      int n = m / 3136;
      int rem = m - n*3136;     // float4 never straddles n (m aligned to 4)
      float4 o;
      o.x = acc[mf][nn][0] + bvs;
      o.y = acc[mf][nn][1] + bvs;
      o.z = acc[mf][nn][2] + bvs;
      o.w = acc[mf][nn][3] + bvs;
      *(float4*)(out + ((size_t)(n*OCN + oc))*3136 + rem) = o;
    }
  }
}

extern "C" void kernel_launch(void* const* d_in, const int* in_sizes, int n_in,
                              void* d_out, int out_size, void* d_ws, size_t ws_size,
                              hipStream_t stream) {
  const float* x    = (const float*)d_in[0];
  const float* wval = (const float*)d_in[1];
  const int*   widx = (const int*)d_in[2];
  const float* bias = (const float*)d_in[3];
  float* out = (float*)d_out;
  const int nnz = in_sizes[1];

  char* ws = (char*)d_ws;
  ushort* xp  = (ushort*)ws;                              // 55.1 MB
  float*  wd  = (float*)(ws + XP_BYTES);                  // 2.36 MB
  ushort* bm3 = (ushort*)(ws + XP_BYTES + WD_BYTES);      // 1.125 MB (frag-order B)

  hipMemsetAsync(wd, 0, WD_BYTES, stream);
  k_transpose<<<dim3(HP, NBATCH), 256, 0, stream>>>(x, xp);
  k_scatter<<<dim3((nnz + 255)/256), 256, 0, stream>>>(widx, wval, wd, nnz);
  k_convert3<<<dim3((KTOT/64*2*16*64)/256), 256, 0, stream>>>(wd, bm3);
  k_gemm8<<<dim3(MTOT/BM), 512, 0, stream>>>(xp, bm3, bias, out);
}